// Round 4
// baseline (507.397 us; speedup 1.0000x reference)
//
#include <hip/hip_runtime.h>
#include <math.h>

#define L2C   65536
#define NC    (2 * L2C)
#define FINC  8
#define FOUTC 8
#define KC    13
#define BLOCK 256         // 4 waves per block
#define EPB   4           // edges per block (1 edge per wave)

constexpr double E_D = 2.71828182845904523536;
constexpr float SCALE_F = (float)((2.0 + 2.0 * E_D) / (E_D - 1.0));

// d_ws layout:
//   [0, 256)                     : mask-encoding flag (1 = 4-byte words, 0 = bytes)
//   [256, 256 + 13.6 MB)         : cmp — 13 raw u64 ballots per edge (both branches)
//   [XT_OFF, XT_OFF + 4 MiB)     : xt — x transposed to (N, FIN)
#define CMP_OFF   256
#define CMP_BYTES ((size_t)NC * KC * 8)
#define XT_OFF    (CMP_OFF + CMP_BYTES)
#define XT_BYTES  ((size_t)NC * FINC * 4)

// For 4-byte encodings (int32 0/1: bytes 1..3 zero; float32 1.0f = 00 00 80 3f:
// byte 1 zero) every byte at offset%4==1 is 0. For 1-byte bools those offsets
// are random 0/1 -> OR over 4096 samples nonzero w.p. 1-2^-4096.
__global__ __launch_bounds__(256)
void detect_mask_kernel(const unsigned char* __restrict__ m, int* __restrict__ flag) {
    __shared__ int any_nz;
    if (threadIdx.x == 0) any_nz = 0;
    __syncthreads();
    int local = 0;
    for (int e = threadIdx.x; e < 4096; e += 256) local |= m[(size_t)e * 4 + 1];
    if (local) atomicOr(&any_nz, 1);
    __syncthreads();
    if (threadIdx.x == 0) flag[0] = (any_nz == 0) ? 1 : 0;
}

// x (FIN, N) -> xt (N, FIN): a gathered column becomes one 32 B segment.
__global__ __launch_bounds__(256)
void transpose_x_kernel(const float* __restrict__ x, float* __restrict__ xt) {
    int n = blockIdx.x * 256 + threadIdx.x;
    float v[FINC];
#pragma unroll
    for (int i = 0; i < FINC; ++i) v[i] = x[(size_t)i * NC + n];
    float4* dst = reinterpret_cast<float4*>(xt + ((size_t)n << 3));
    dst[0] = make_float4(v[0], v[1], v[2], v[3]);
    dst[1] = make_float4(v[4], v[5], v[6], v[7]);
}

// Pure streaming pass: one wave per edge, 13 coalesced loads off one base
// address (immediate offsets t*256 B), ballot-compress 832 words -> 13 u64,
// one 104 B store. VALU ~80/wave vs 328 CU-cyc of HBM -> BW-bound.
__global__ __launch_bounds__(BLOCK)
void mask_compress_kernel(const int* __restrict__ flag_p,
                          const unsigned char* __restrict__ mh,
                          const unsigned char* __restrict__ mv,
                          unsigned long long* __restrict__ cmp)
{
    const int tid  = threadIdx.x;
    const int lane = tid & 63;
    const int e    = blockIdx.x * EPB + (tid >> 6);    // 0 .. 2*L2C-1
    const bool hor = (e < L2C);
    const unsigned char* mask = hor ? mh : mv;
    const int be = hor ? e : e - L2C;

    unsigned long long myb = 0;                        // lane t<13 keeps ballot t
    if (flag_p[0]) {
        const unsigned int* src =
            reinterpret_cast<const unsigned int*>(mask) + (size_t)be * 832 + lane;
        unsigned int w[KC];
#pragma unroll
        for (int t = 0; t < KC; ++t) w[t] = src[t * 64]; // one base + offset:t*256
#pragma unroll
        for (int t = 0; t < KC; ++t) {
            unsigned long long bal = __ballot(w[t] != 0u);  // bit l = word t*64+l
            if (lane == t) myb = bal;
        }
    } else {
        const unsigned char* src = mask + (size_t)be * 832 + lane;
        unsigned char w[KC];
#pragma unroll
        for (int t = 0; t < KC; ++t) w[t] = src[t * 64];
#pragma unroll
        for (int t = 0; t < KC; ++t) {
            unsigned long long bal = __ballot(w[t] != 0);
            if (lane == t) myb = bal;
        }
    }
    if (lane < KC) cmp[(size_t)e * KC + lane] = myb;
}

// One wave per edge, lane = o*8 + i. Reads 104 B of ballots + 52 B ker +
// 13 gathered 32 B xt segments (L2-resident). use_pre=0 falls back to the
// R3 fused ballot path (no pre-pass, masks read here).
__global__ __launch_bounds__(BLOCK)
void edge_conv_kernel(const float* __restrict__ xt,
                      const unsigned long long* __restrict__ cmp, int use_pre,
                      const int* __restrict__ flag_p,
                      const float* __restrict__ Wh, const float* __restrict__ Wv,
                      const float* __restrict__ bh, const float* __restrict__ bv,
                      const unsigned char* __restrict__ mh,
                      const unsigned char* __restrict__ mv,
                      const int* __restrict__ kh, const int* __restrict__ kv,
                      float* __restrict__ out)
{
    __shared__ float Wsh[FOUTC * FINC * KC];   // flat [o][i][k], same as input

    const int tid  = threadIdx.x;
    const int lane = tid & 63;
    const int o    = lane >> 3;
    const int i    = lane & 7;

    const int blk = blockIdx.x;
    const int blocks_per_branch = L2C / EPB;   // 16384
    const bool hor = (blk < blocks_per_branch);

    const float*         W    = hor ? Wh  : Wv;
    const float*         bias = hor ? bh  : bv;
    const unsigned char* mask = hor ? mh  : mv;
    const int*           ker  = hor ? kh  : kv;
    const int bblk = hor ? blk : blk - blocks_per_branch;
    const int be   = bblk * EPB + (tid >> 6);  // edge within branch
    const int col  = hor ? be : (be + L2C);    // edge lists are arange / arange+L2
    const int eg   = col;                      // global edge id (cmp index)

    for (int j = tid; j < FOUTC * FINC * KC; j += BLOCK) Wsh[j] = W[j];
    __syncthreads();

    // lane t<13 holds ballot t (bit l = flat mask word t*64+l of this edge)
    unsigned long long myb = 0;
    int colv = 0;
    if (use_pre) {
        if (lane < KC) {
            myb  = cmp[(size_t)eg * KC + lane];
            colv = ker[(size_t)be * KC + lane];
        }
    } else {
        if (lane < KC) colv = ker[(size_t)be * KC + lane];
        if (flag_p[0]) {
            const unsigned int* mw =
                reinterpret_cast<const unsigned int*>(mask) + (size_t)be * 832 + lane;
#pragma unroll
            for (int t = 0; t < KC; ++t) {
                unsigned long long bal = __ballot(mw[t * 64] != 0u);
                if (lane == t) myb = bal;
            }
        } else {
            const unsigned char* mb = mask + (size_t)be * 832 + lane;
#pragma unroll
            for (int t = 0; t < KC; ++t) {
                unsigned long long bal = __ballot(mb[t * 64] != 0);
                if (lane == t) myb = bal;
            }
        }
    }

    // Extract this lane's 13 row bits (flat bits lane*13 .. lane*13+12).
    const int s     = lane * KC;
    const int u0    = s >> 6;                  // 0..12
    const int shift = s & 63;
    unsigned long long lo = __shfl(myb, u0);
    unsigned long long hi = __shfl(myb, u0 + 1);   // lane 13 holds 0, safe
    unsigned int mbits = (unsigned int)(lo >> shift);
    if (shift) mbits |= (unsigned int)(hi << (64 - shift));
    mbits &= 0x1FFFu;

    float wreg[KC];
#pragma unroll
    for (int k = 0; k < KC; ++k) wreg[k] = Wsh[lane * KC + k];  // 2-way alias: free

    float acc = 0.0f;
#pragma unroll
    for (int k = 0; k < KC; ++k) {
        const int c  = __shfl(colv, k);                  // wave-uniform column
        const float xv = xt[((size_t)c << 3) + i];       // one 32 B seg / wave / k
        const float wm = ((mbits >> k) & 1u) ? wreg[k] : 0.0f;
        acc = fmaf(wm, xv, acc);
    }

    acc += __shfl_xor(acc, 1);
    acc += __shfl_xor(acc, 2);
    acc += __shfl_xor(acc, 4);

    if (i == 0) {
        const float z   = acc + bias[o];
        const float sig = 1.0f / (1.0f + __expf(-z));
        out[(size_t)o * NC + col] = (sig - 0.5f) * SCALE_F;
    }
}

extern "C" void kernel_launch(void* const* d_in, const int* in_sizes, int n_in,
                              void* d_out, int out_size, void* d_ws, size_t ws_size,
                              hipStream_t stream) {
    const float*         x   = (const float*)d_in[0];
    const float*         Wh  = (const float*)d_in[1];
    const float*         Wv  = (const float*)d_in[2];
    const float*         bh  = (const float*)d_in[3];
    const float*         bv  = (const float*)d_in[4];
    const unsigned char* mh  = (const unsigned char*)d_in[5];
    const unsigned char* mv  = (const unsigned char*)d_in[6];
    const int*           kh  = (const int*)d_in[7];
    const int*           kv  = (const int*)d_in[8];
    float* out  = (float*)d_out;
    int*   flag = (int*)d_ws;

    const int use_pre = (ws_size >= XT_OFF + XT_BYTES) ? 1 : 0;
    unsigned long long* cmp = (unsigned long long*)((char*)d_ws + CMP_OFF);
    float* xt = use_pre ? (float*)((char*)d_ws + XT_OFF)
                        : (float*)((char*)d_ws + 256);   // R3 layout fallback

    detect_mask_kernel<<<1, 256, 0, stream>>>(mh, flag);
    if (use_pre) {
        mask_compress_kernel<<<NC / EPB, BLOCK, 0, stream>>>(flag, mh, mv, cmp);
    }
    transpose_x_kernel<<<NC / 256, 256, 0, stream>>>(x, xt);
    edge_conv_kernel<<<NC / EPB, BLOCK, 0, stream>>>(
        xt, cmp, use_pre, flag, Wh, Wv, bh, bv, mh, mv, kh, kv, out);
}

// Round 5
// 453.374 us; speedup vs baseline: 1.1192x; 1.1192x over previous
//
#include <hip/hip_runtime.h>
#include <math.h>

#define L2C   65536
#define NC    (2 * L2C)
#define FINC  8
#define FOUTC 8
#define KC    13
#define BLOCK 256          // 4 waves/block
#define EPW   4            // edges per wave (832*4 words = 13 uint4-loads of 64 lanes)
#define EPB   16           // edges per block

constexpr double E_D = 2.71828182845904523536;
constexpr float SCALE_F = (float)((2.0 + 2.0 * E_D) / (E_D - 1.0));

// d_ws: [0,256) mask-encoding flag (1 = 4-byte words, 0 = 1-byte bools);
//       [256, 256+4MiB) xt = x transposed to (N, FIN).

// For 4-byte encodings (int32 0/1 and float32 0.0/1.0f) every byte at
// offset%4==1 is zero; for 1-byte bools those offsets are random 0/1.
__global__ __launch_bounds__(256)
void detect_mask_kernel(const unsigned char* __restrict__ m, int* __restrict__ flag) {
    __shared__ int any_nz;
    if (threadIdx.x == 0) any_nz = 0;
    __syncthreads();
    int local = 0;
    for (int e = threadIdx.x; e < 4096; e += 256) local |= m[(size_t)e * 4 + 1];
    if (local) atomicOr(&any_nz, 1);
    __syncthreads();
    if (threadIdx.x == 0) flag[0] = (any_nz == 0) ? 1 : 0;
}

// x (FIN, N) -> xt (N, FIN): a gathered column becomes one 32 B segment.
__global__ __launch_bounds__(256)
void transpose_x_kernel(const float* __restrict__ x, float* __restrict__ xt) {
    int n = blockIdx.x * 256 + threadIdx.x;
    float v[FINC];
#pragma unroll
    for (int i = 0; i < FINC; ++i) v[i] = x[(size_t)i * NC + n];
    float4* dst = reinterpret_cast<float4*>(xt + ((size_t)n << 3));
    dst[0] = make_float4(v[0], v[1], v[2], v[3]);
    dst[1] = make_float4(v[4], v[5], v[6], v[7]);
}

// Fused: one wave per 4 edges. 13 uint4 loads stream the mask (13.3 KB in
// flight per wave); nz bytes round-trip through a wave-private LDS buffer.
__global__ __launch_bounds__(BLOCK)
void edge_conv_kernel(const float* __restrict__ xt,
                      const int* __restrict__ flag_p,
                      const float* __restrict__ Wh, const float* __restrict__ Wv,
                      const float* __restrict__ bh, const float* __restrict__ bv,
                      const unsigned char* __restrict__ mh,
                      const unsigned char* __restrict__ mv,
                      const int* __restrict__ kh, const int* __restrict__ kv,
                      float* __restrict__ out)
{
    __shared__ float Wsh[FOUTC * FINC * KC];          // flat [o][i][k]
    __shared__ unsigned char nzbuf[4][EPW * 832];     // per-wave nz bytes (word idx)

    const int tid  = threadIdx.x;
    const int lane = tid & 63;
    const int w    = tid >> 6;
    const int o    = lane >> 3;
    const int i    = lane & 7;

    const int blk = blockIdx.x;
    const int blocks_per_branch = L2C / EPB;          // 4096
    const bool hor = (blk < blocks_per_branch);

    const float*         W    = hor ? Wh  : Wv;
    const float*         bias = hor ? bh  : bv;
    const unsigned char* mask = hor ? mh  : mv;
    const int*           ker  = hor ? kh  : kv;
    const int bblk = hor ? blk : blk - blocks_per_branch;
    const int be0  = bblk * EPB + w * EPW;            // first of 4 edges (branch-local)
    const int c0   = hor ? be0 : be0 + L2C;           // first output column

    // ker rows for 4 edges: 52 contiguous ints.
    int colv = 0;
    if (lane < EPW * KC) colv = ker[(size_t)be0 * KC + lane];

    for (int j = tid; j < FOUTC * FINC * KC; j += BLOCK) Wsh[j] = W[j];
    __syncthreads();

    float wreg[KC];
#pragma unroll
    for (int k = 0; k < KC; ++k) wreg[k] = Wsh[lane * KC + k];  // 2-way alias: free

    unsigned char* nz = &nzbuf[w][0];

    if (flag_p[0]) {
        // word masks: 4 edges = 3328 words = 13 x (64 lanes x uint4)
        const uint4* src = reinterpret_cast<const uint4*>(
            reinterpret_cast<const unsigned int*>(mask) + (size_t)be0 * 832) + lane;
        uint4 v[KC];
#pragma unroll
        for (int t = 0; t < KC; ++t) v[t] = src[t * 64];
#pragma unroll
        for (int t = 0; t < KC; ++t) {
            unsigned int b4 = (v[t].x ? 0x01u : 0u) | (v[t].y ? 0x0100u : 0u) |
                              (v[t].z ? 0x010000u : 0u) | (v[t].w ? 0x01000000u : 0u);
            reinterpret_cast<unsigned int*>(nz)[t * 64 + lane] = b4;  // stride-1
        }
    } else {
        // byte masks: 4 edges = 3328 bytes = 208 uint4; copy raw 0/1 bytes.
        const uint4* src = reinterpret_cast<const uint4*>(mask + (size_t)be0 * 832);
#pragma unroll
        for (int t = 0; t < 4; ++t) {
            int idx = t * 64 + lane;
            if (idx < 208) reinterpret_cast<uint4*>(nz)[idx] = src[idx];
        }
    }
    // No barrier: nzbuf[w] is wave-private; compiler inserts lgkmcnt waits.

    float accs[EPW];
#pragma unroll
    for (int e = 0; e < EPW; ++e) {
        float acc = 0.0f;
#pragma unroll
        for (int k = 0; k < KC; ++k) {
            const int c    = __shfl(colv, e * KC + k);      // wave-uniform column
            const float xv = xt[((size_t)c << 3) + i];      // one 32 B seg / instr
            const unsigned char mb = nz[e * 832 + lane * KC + k];
            acc = fmaf(mb ? wreg[k] : 0.0f, xv, acc);
        }
        accs[e] = acc;
    }

    // Reduce over i within each o-group; all 8 lanes end with the sum.
#pragma unroll
    for (int e = 0; e < EPW; ++e) {
        accs[e] += __shfl_xor(accs[e], 1);
        accs[e] += __shfl_xor(accs[e], 2);
        accs[e] += __shfl_xor(accs[e], 4);
    }

    // Lane (o, i<4) stores edge i at out[o*NC + c0+i]: 8 x 16 B segments, 1 instr.
    if (i < EPW) {
        const float z   = accs[i] + bias[o];
        const float sig = 1.0f / (1.0f + __expf(-z));
        out[(size_t)o * NC + c0 + i] = (sig - 0.5f) * SCALE_F;
    }
}

extern "C" void kernel_launch(void* const* d_in, const int* in_sizes, int n_in,
                              void* d_out, int out_size, void* d_ws, size_t ws_size,
                              hipStream_t stream) {
    const float*         x   = (const float*)d_in[0];
    const float*         Wh  = (const float*)d_in[1];
    const float*         Wv  = (const float*)d_in[2];
    const float*         bh  = (const float*)d_in[3];
    const float*         bv  = (const float*)d_in[4];
    const unsigned char* mh  = (const unsigned char*)d_in[5];
    const unsigned char* mv  = (const unsigned char*)d_in[6];
    const int*           kh  = (const int*)d_in[7];
    const int*           kv  = (const int*)d_in[8];
    float* out  = (float*)d_out;
    int*   flag = (int*)d_ws;
    float* xt   = (float*)((char*)d_ws + 256);

    detect_mask_kernel<<<1, 256, 0, stream>>>(mh, flag);
    transpose_x_kernel<<<NC / 256, 256, 0, stream>>>(x, xt);
    edge_conv_kernel<<<NC / EPB, BLOCK, 0, stream>>>(
        xt, flag, Wh, Wv, bh, bv, mh, mv, kh, kv, out);
}